// Round 1
// baseline (105.620 us; speedup 1.0000x reference)
//
#include <hip/hip_runtime.h>
#include <math.h>

// GBST fused kernel for MI355X.
// B=16, L=3072, H=256, VOCAB=256, MAX_BLOCK=4, DOWNSAMPLE=2.
// L divisible by 1,2,3,4 -> all ceil-mode pools are exact means.
// Chunk of 48 positions (multiple of lcm(1..4)=12) is self-contained.

#define BATCH   16
#define SEQ     3072
#define EMBED   256
#define VOCAB   256
#define CHUNK   48
#define OUTROWS 24                 // CHUNK / DOWNSAMPLE
#define NCHUNK  (SEQ / CHUNK)      // 64
#define OUTL    (SEQ / 2)          // 1536

// Precomputed tables (rewritten every call by precompute_kernel; harness only
// poisons d_out/d_ws, and we overwrite these fully each launch anyway).
__device__ float g_pe[4 * EMBED];
__device__ float g_yv[VOCAB];
__device__ float g_pedot[4];

__device__ inline float4 f4add(float4 a, float4 b) {
    return make_float4(a.x + b.x, a.y + b.y, a.z + b.z, a.w + b.w);
}
__device__ inline float4 f4fma(float4 acc, float s, float4 a) {
    acc.x += s * a.x; acc.y += s * a.y; acc.z += s * a.z; acc.w += s * a.w;
    return acc;
}

__global__ __launch_bounds__(256) void precompute_kernel(
        const float* __restrict__ E, const float* __restrict__ w) {
    __shared__ float w_s[EMBED];
    __shared__ float pe_s[4 * EMBED];
    const int tid = threadIdx.x;

    w_s[tid] = w[tid];

    // Sinusoidal PE. numpy promotes the angle computation to float64
    // (float32 array * np.float64 scalar), so compute in double and cast.
    {
        const int i = tid >> 1;
        const double div = exp((double)(2 * i) * (-log(10000.0) / 256.0));
        #pragma unroll
        for (int q = 0; q < 4; ++q) {
            const double ang = (double)q * div;
            const float v = (tid & 1) ? (float)cos(ang) : (float)sin(ang);
            pe_s[q * EMBED + tid] = v;
            g_pe[q * EMBED + tid] = v;
        }
    }
    __syncthreads();

    // yv[v] = dot(E[v], w). 4 waves, each wave does 64 rows with coalesced
    // float4 row loads + wave shuffle reduction.
    const int wave = tid >> 6, lane = tid & 63;
    const float4* E4 = (const float4*)E;
    for (int rr = 0; rr < 64; ++rr) {
        const int v = wave * 64 + rr;
        const float4 e = E4[v * 64 + lane];
        const float4 ww = *(const float4*)&w_s[lane * 4];
        float d = e.x * ww.x + e.y * ww.y + e.z * ww.z + e.w * ww.w;
        #pragma unroll
        for (int off = 32; off > 0; off >>= 1) d += __shfl_down(d, off);
        if (lane == 0) g_yv[v] = d;
    }

    // pedot[q] = dot(pe[q], w)
    if (tid < 4) {
        float s = 0.f;
        for (int h = 0; h < EMBED; ++h) s += pe_s[tid * EMBED + h] * w_s[h];
        g_pedot[tid] = s;
    }
}

__global__ __launch_bounds__(256) void gbst_kernel(
        const int* __restrict__ ids, const float* __restrict__ E,
        const float* __restrict__ b_score, float* __restrict__ out) {
    __shared__ float4 x_s[CHUNK * 64];   // 48 KB: x = E[id] + pe, [48][256] f32
    __shared__ int    id_s[CHUNK];
    __shared__ float  y_s[CHUNK];        // per-position score dot
    __shared__ float4 c_s[CHUNK];        // post-calibration coeffs, /m folded

    const int tid   = threadIdx.x;
    const int b     = blockIdx.x >> 6;   // NCHUNK = 64
    const int chunk = blockIdx.x & 63;
    const int pos0  = chunk * CHUNK;
    const int wave  = tid >> 6, lane = tid & 63;

    if (tid < CHUNK) id_s[tid] = ids[b * SEQ + pos0 + tid];
    __syncthreads();

    // Stage x into LDS. Each wave loads one full 1KB row per iteration
    // (64 lanes x float4) -> fully coalesced gather from E (L2-resident).
    const float4* E4  = (const float4*)E;
    const float4* pe4 = (const float4*)g_pe;
    #pragma unroll
    for (int k = 0; k < 12; ++k) {
        const int t = k * 4 + wave;
        const float4 e = E4[id_s[t] * 64 + lane];
        const float4 p = pe4[(t & 3) * 64 + lane];   // pos0 % 4 == 0
        x_s[t * 64 + lane] = f4add(e, p);
    }
    if (tid < CHUNK) y_s[tid] = g_yv[id_s[tid]] + g_pedot[tid & 3];
    __syncthreads();

    // Per-position: window-mean scores -> softmax over m -> 4x4 score
    // calibration -> coefficients c[m] = s_new[m] / (m+1).
    if (tid < CHUNK) {
        const int l = tid;
        const float bsc = b_score[0];
        const float m1 = y_s[l];
        const int l2 = l & ~1;
        const float m2 = 0.5f * (y_s[l2] + y_s[l2 + 1]);
        const int l3 = (l / 3) * 3;
        const float m3 = (1.f / 3.f) * (y_s[l3] + y_s[l3 + 1] + y_s[l3 + 2]);
        const int l4 = l & ~3;
        const float m4 = 0.25f * (y_s[l4] + y_s[l4+1] + y_s[l4+2] + y_s[l4+3]);

        float sc[4] = {m1 + bsc, m2 + bsc, m3 + bsc, m4 + bsc};
        float mx = fmaxf(fmaxf(sc[0], sc[1]), fmaxf(sc[2], sc[3]));
        float p[4], sum = 0.f;
        #pragma unroll
        for (int m = 0; m < 4; ++m) { p[m] = expf(sc[m] - mx); sum += p[m]; }
        const float inv = 1.f / sum;
        #pragma unroll
        for (int m = 0; m < 4; ++m) p[m] *= inv;

        float snew[4];
        #pragma unroll
        for (int i = 0; i < 4; ++i) {
            const float q0 = p[i]*p[0], q1 = p[i]*p[1], q2 = p[i]*p[2], q3 = p[i]*p[3];
            const float mq = fmaxf(fmaxf(q0, q1), fmaxf(q2, q3));
            const float e0 = expf(q0 - mq), e1 = expf(q1 - mq),
                        e2 = expf(q2 - mq), e3 = expf(q3 - mq);
            snew[i] = (e0*p[0] + e1*p[1] + e2*p[2] + e3*p[3]) / (e0+e1+e2+e3);
        }
        c_s[l] = make_float4(snew[0], snew[1] * 0.5f,
                             snew[2] * (1.f / 3.f), snew[3] * 0.25f);
    }
    __syncthreads();

    // Combine + fold the final avg_pool(k=2): rows 2r and 2r+1 share their
    // bs=2 window (S2 = x0+x1) and bs=4 window (2r..2r|3 in one 4-block).
    #pragma unroll
    for (int k = 0; k < 6; ++k) {
        const int r  = wave * 6 + k;
        const int l0 = 2 * r, l1 = l0 + 1;

        const float4 x0 = x_s[l0 * 64 + lane];
        const float4 x1 = x_s[l1 * 64 + lane];
        const float4 S2 = f4add(x0, x1);

        const int b4 = l0 & ~3;
        const float4 S4 = f4add(f4add(x_s[b4*64 + lane], x_s[(b4+1)*64 + lane]),
                                f4add(x_s[(b4+2)*64 + lane], x_s[(b4+3)*64 + lane]));

        const int j3a = l0 / 3, j3b = l1 / 3;
        const int t3a = 3 * j3a;
        const float4 S3a = f4add(f4add(x_s[t3a*64 + lane], x_s[(t3a+1)*64 + lane]),
                                 x_s[(t3a+2)*64 + lane]);
        float4 S3b = S3a;
        if (j3b != j3a) {                       // wave-uniform branch
            const int t3b = 3 * j3b;
            S3b = f4add(f4add(x_s[t3b*64 + lane], x_s[(t3b+1)*64 + lane]),
                        x_s[(t3b+2)*64 + lane]);
        }

        const float4 ca = c_s[l0];              // broadcast reads
        const float4 cb = c_s[l1];

        float4 acc = make_float4(0.f, 0.f, 0.f, 0.f);
        acc = f4fma(acc, ca.x, x0);
        acc = f4fma(acc, cb.x, x1);
        acc = f4fma(acc, ca.y + cb.y, S2);
        acc = f4fma(acc, ca.z, S3a);
        acc = f4fma(acc, cb.z, S3b);
        acc = f4fma(acc, ca.w + cb.w, S4);
        acc.x *= 0.5f; acc.y *= 0.5f; acc.z *= 0.5f; acc.w *= 0.5f;

        ((float4*)out)[(b * OUTL + chunk * OUTROWS + r) * 64 + lane] = acc;
    }
}

extern "C" void kernel_launch(void* const* d_in, const int* in_sizes, int n_in,
                              void* d_out, int out_size, void* d_ws, size_t ws_size,
                              hipStream_t stream) {
    const int*   ids = (const int*)d_in[0];
    const float* E   = (const float*)d_in[1];
    const float* w   = (const float*)d_in[2];
    const float* bsc = (const float*)d_in[3];
    float*       out = (float*)d_out;

    precompute_kernel<<<1, 256, 0, stream>>>(E, w);
    gbst_kernel<<<BATCH * NCHUNK, 256, 0, stream>>>(ids, E, bsc, out);
}

// Round 2
// 82.673 us; speedup vs baseline: 1.2776x; 1.2776x over previous
//
#include <hip/hip_runtime.h>
#include <math.h>

// GBST fused single-kernel for MI355X.
// B=16, L=3072, H=256, VOCAB=256, MAX_BLOCK=4, DOWNSAMPLE=2.
// L divisible by 1,2,3,4 -> all ceil-mode pools are exact means.
// Chunk of 48 positions (multiple of lcm(1..4)=12) is self-contained.
//
// R1 lesson: the separate 1-block precompute kernel was 45us of pure serial
// latency (cold loads + dependent shuffle chains, fp64 libm). PE is now
// computed per-block in f32 (error ~1e-7 << 7.8e-3 passing absmax) and the
// score dot y[t]=dot(x[t],w) is folded into the LDS staging loop.

#define BATCH   16
#define SEQ     3072
#define EMBED   256
#define CHUNK   48
#define OUTROWS 24                 // CHUNK / DOWNSAMPLE
#define NCHUNK  (SEQ / CHUNK)      // 64
#define OUTL    (SEQ / 2)          // 1536

__device__ inline float4 f4add(float4 a, float4 b) {
    return make_float4(a.x + b.x, a.y + b.y, a.z + b.z, a.w + b.w);
}
__device__ inline float4 f4fma(float4 acc, float s, float4 a) {
    acc.x += s * a.x; acc.y += s * a.y; acc.z += s * a.z; acc.w += s * a.w;
    return acc;
}

__global__ __launch_bounds__(256) void gbst_kernel(
        const int* __restrict__ ids, const float* __restrict__ E,
        const float* __restrict__ w, const float* __restrict__ b_score,
        float* __restrict__ out) {
    __shared__ float4 x_s[CHUNK * 64];   // 48 KB: x = E[id] + pe, [48][256] f32
    __shared__ float4 pe_s4[4 * 64];     // 4 KB: pe[4][256]
    __shared__ float4 w_s4[64];          // 1 KB
    __shared__ int    id_s[CHUNK];
    __shared__ float  y_s[CHUNK];        // per-position score dot
    __shared__ float4 c_s[CHUNK];        // post-calibration coeffs, /m folded

    const int tid   = threadIdx.x;
    const int b     = blockIdx.x >> 6;   // NCHUNK = 64
    const int chunk = blockIdx.x & 63;
    const int pos0  = chunk * CHUNK;
    const int wave  = tid >> 6, lane = tid & 63;

    // Issue global loads first so their latency hides under the PE math.
    if (tid < CHUNK) id_s[tid] = ids[b * SEQ + pos0 + tid];
    ((float*)w_s4)[tid] = w[tid];

    // Sinusoidal PE in f32 (ref computes in f64 then casts; f32 err ~1e-7).
    {
        float* pe_sf = (float*)pe_s4;
        const int i = tid >> 1;
        const float div = expf((float)(2 * i) * -0.03597789207803197f);
        #pragma unroll
        for (int q = 0; q < 4; ++q) {
            const float ang = (float)q * div;
            pe_sf[q * EMBED + tid] = (tid & 1) ? cosf(ang) : sinf(ang);
        }
    }
    __syncthreads();

    // Stage x into LDS and fold in the score dot. Each wave handles 12
    // positions; per position: 64 lanes x float4 coalesced row gather from E
    // (L2-resident), add PE, store to LDS, dot with w, shuffle-reduce.
    const float4* E4 = (const float4*)E;
    #pragma unroll
    for (int k = 0; k < 12; ++k) {
        const int t = k * 4 + wave;
        const float4 e = E4[id_s[t] * 64 + lane];
        const float4 p = pe_s4[(t & 3) * 64 + lane];   // pos0 % 4 == 0
        const float4 x = f4add(e, p);
        x_s[t * 64 + lane] = x;
        const float4 ww = w_s4[lane];
        float d = x.x * ww.x + x.y * ww.y + x.z * ww.z + x.w * ww.w;
        #pragma unroll
        for (int off = 32; off > 0; off >>= 1) d += __shfl_down(d, off);
        if (lane == 0) y_s[t] = d;
    }
    __syncthreads();

    // Per-position: window-mean scores -> softmax over m -> 4x4 score
    // calibration -> coefficients c[m] = s_new[m] / (m+1).
    if (tid < CHUNK) {
        const int l = tid;
        const float bsc = b_score[0];
        const float m1 = y_s[l];
        const int l2 = l & ~1;
        const float m2 = 0.5f * (y_s[l2] + y_s[l2 + 1]);
        const int l3 = (l / 3) * 3;
        const float m3 = (1.f / 3.f) * (y_s[l3] + y_s[l3 + 1] + y_s[l3 + 2]);
        const int l4 = l & ~3;
        const float m4 = 0.25f * (y_s[l4] + y_s[l4+1] + y_s[l4+2] + y_s[l4+3]);

        float sc[4] = {m1 + bsc, m2 + bsc, m3 + bsc, m4 + bsc};
        float mx = fmaxf(fmaxf(sc[0], sc[1]), fmaxf(sc[2], sc[3]));
        float p[4], sum = 0.f;
        #pragma unroll
        for (int m = 0; m < 4; ++m) { p[m] = expf(sc[m] - mx); sum += p[m]; }
        const float inv = 1.f / sum;
        #pragma unroll
        for (int m = 0; m < 4; ++m) p[m] *= inv;

        float snew[4];
        #pragma unroll
        for (int i = 0; i < 4; ++i) {
            const float q0 = p[i]*p[0], q1 = p[i]*p[1], q2 = p[i]*p[2], q3 = p[i]*p[3];
            const float mq = fmaxf(fmaxf(q0, q1), fmaxf(q2, q3));
            const float e0 = expf(q0 - mq), e1 = expf(q1 - mq),
                        e2 = expf(q2 - mq), e3 = expf(q3 - mq);
            snew[i] = (e0*p[0] + e1*p[1] + e2*p[2] + e3*p[3]) / (e0+e1+e2+e3);
        }
        c_s[l] = make_float4(snew[0], snew[1] * 0.5f,
                             snew[2] * (1.f / 3.f), snew[3] * 0.25f);
    }
    __syncthreads();

    // Combine + fold the final avg_pool(k=2): rows 2r and 2r+1 share their
    // bs=2 window (S2 = x0+x1) and bs=4 window (2r..2r|3 in one 4-block).
    #pragma unroll
    for (int k = 0; k < 6; ++k) {
        const int r  = wave * 6 + k;
        const int l0 = 2 * r, l1 = l0 + 1;

        const float4 x0 = x_s[l0 * 64 + lane];
        const float4 x1 = x_s[l1 * 64 + lane];
        const float4 S2 = f4add(x0, x1);

        const int b4 = l0 & ~3;
        const float4 S4 = f4add(f4add(x_s[b4*64 + lane], x_s[(b4+1)*64 + lane]),
                                f4add(x_s[(b4+2)*64 + lane], x_s[(b4+3)*64 + lane]));

        const int j3a = l0 / 3, j3b = l1 / 3;
        const int t3a = 3 * j3a;
        const float4 S3a = f4add(f4add(x_s[t3a*64 + lane], x_s[(t3a+1)*64 + lane]),
                                 x_s[(t3a+2)*64 + lane]);
        float4 S3b = S3a;
        if (j3b != j3a) {                       // wave-uniform branch
            const int t3b = 3 * j3b;
            S3b = f4add(f4add(x_s[t3b*64 + lane], x_s[(t3b+1)*64 + lane]),
                        x_s[(t3b+2)*64 + lane]);
        }

        const float4 ca = c_s[l0];              // broadcast reads
        const float4 cb = c_s[l1];

        float4 acc = make_float4(0.f, 0.f, 0.f, 0.f);
        acc = f4fma(acc, ca.x, x0);
        acc = f4fma(acc, cb.x, x1);
        acc = f4fma(acc, ca.y + cb.y, S2);
        acc = f4fma(acc, ca.z, S3a);
        acc = f4fma(acc, cb.z, S3b);
        acc = f4fma(acc, ca.w + cb.w, S4);
        acc.x *= 0.5f; acc.y *= 0.5f; acc.z *= 0.5f; acc.w *= 0.5f;

        ((float4*)out)[(b * OUTL + chunk * OUTROWS + r) * 64 + lane] = acc;
    }
}

extern "C" void kernel_launch(void* const* d_in, const int* in_sizes, int n_in,
                              void* d_out, int out_size, void* d_ws, size_t ws_size,
                              hipStream_t stream) {
    const int*   ids = (const int*)d_in[0];
    const float* E   = (const float*)d_in[1];
    const float* w   = (const float*)d_in[2];
    const float* bsc = (const float*)d_in[3];
    float*       out = (float*)d_out;

    gbst_kernel<<<BATCH * NCHUNK, 256, 0, stream>>>(ids, E, w, bsc, out);
}

// Round 3
// 76.222 us; speedup vs baseline: 1.3857x; 1.0846x over previous
//
#include <hip/hip_runtime.h>
#include <math.h>

// GBST fused single-kernel for MI355X — register-resident version.
// B=16, L=3072, H=256, VOCAB=256, MAX_BLOCK=4, DOWNSAMPLE=2.
//
// One 64-lane wave owns one 12-position group (12 = lcm(1..4), and 12 | SEQ,
// so every bs-window and the k=2 output pool are group-local). Lane = float4
// h-slice. x[12] lives in registers; scores via 12 butterfly shfl_xor
// reductions; per-position softmax+calibration on lanes 0..11; coefficients
// re-broadcast with __shfl. No LDS tile, no __syncthreads, no inter-wave
// coupling -> 4096 independent waves.
//
// R2 lesson: 48KB-LDS blocks (3/CU) with two block-wide barriers were
// latency-bound (~36us). R1 lesson: no separate precompute dispatch.

#define BATCH 16
#define SEQ   3072
#define EMBED 256
#define OUTL  (SEQ / 2)            // 1536
#define GPB   (SEQ / 12)           // 256 groups per batch
#define WPB   4                    // waves per block
#define NBLK  (BATCH * GPB / WPB)  // 1024

__device__ inline float4 f4add(float4 a, float4 b) {
    return make_float4(a.x + b.x, a.y + b.y, a.z + b.z, a.w + b.w);
}
__device__ inline float4 f4fma(float4 acc, float s, float4 a) {
    acc.x += s * a.x; acc.y += s * a.y; acc.z += s * a.z; acc.w += s * a.w;
    return acc;
}
__device__ inline float dot4(float4 a, float4 b) {
    return a.x * b.x + a.y * b.y + a.z * b.z + a.w * b.w;
}

// Constant-operand select trees (all register cndmasks; no local arrays).
__device__ inline float sel12(int i, float a0, float a1, float a2, float a3,
                              float a4, float a5, float a6, float a7,
                              float a8, float a9, float a10, float a11) {
    return i == 0 ? a0 : i == 1 ? a1 : i == 2 ? a2 : i == 3 ? a3 :
           i == 4 ? a4 : i == 5 ? a5 : i == 6 ? a6 : i == 7 ? a7 :
           i == 8 ? a8 : i == 9 ? a9 : i == 10 ? a10 : a11;
}
__device__ inline float sel6(int i, float a0, float a1, float a2,
                             float a3, float a4, float a5) {
    return i == 0 ? a0 : i == 1 ? a1 : i == 2 ? a2 :
           i == 3 ? a3 : i == 4 ? a4 : a5;
}
__device__ inline float sel4(int i, float a0, float a1, float a2, float a3) {
    return i == 0 ? a0 : i == 1 ? a1 : i == 2 ? a2 : a3;
}
__device__ inline float sel3(int i, float a0, float a1, float a2) {
    return i == 0 ? a0 : i == 1 ? a1 : a2;
}

__global__ __launch_bounds__(256) void gbst_kernel(
        const int* __restrict__ ids, const float* __restrict__ E,
        const float* __restrict__ w, const float* __restrict__ b_score,
        float* __restrict__ out) {
    const int tid  = threadIdx.x;
    const int wave = tid >> 6, lane = tid & 63;
    const int grp  = blockIdx.x * WPB + wave;
    const int b    = grp >> 8;          // GPB = 256
    const int g    = grp & 255;
    const int pos0 = g * 12;            // divisible by 12 -> by 2,3,4

    // Issue all global loads early; latency hides under the PE trig.
    const float4* E4 = (const float4*)E;
    const float4 w4  = ((const float4*)w)[lane];
    const float bias = b_score[0];
    int idv = 0;
    if (lane < 12) idv = ids[b * SEQ + pos0 + lane];

    // Sinusoidal PE for this lane's h-slice (h = 4*lane .. 4*lane+3).
    // div[j] = exp(2j * -ln(1e4)/256); even h -> sin, odd h -> cos.
    const float c1 = -0.035977892080032f;
    const float da = expf((float)(4 * lane) * c1);
    const float db = expf((float)(4 * lane + 2) * c1);
    const float4 pe1 = make_float4(sinf(da), cosf(da), sinf(db), cosf(db));
    const float4 pe2 = make_float4(sinf(2.f*da), cosf(2.f*da), sinf(2.f*db), cosf(2.f*db));
    const float4 pe3 = make_float4(sinf(3.f*da), cosf(3.f*da), sinf(3.f*db), cosf(3.f*db));

    // x[t] = E[id[t]] + pe[(pos0+t)&3], pos0%4==0 -> index t&3.
    float4 x[12];
    #pragma unroll
    for (int t = 0; t < 12; ++t) {
        const int idt = __shfl(idv, t);
        const float4 e = E4[idt * 64 + lane];
        const float4 p = (t & 3) == 0 ? make_float4(0.f, 1.f, 0.f, 1.f)
                       : (t & 3) == 1 ? pe1 : (t & 3) == 2 ? pe2 : pe3;
        x[t] = f4add(e, p);
    }

    // y[t] = dot(x[t], w): per-lane partial + full-wave butterfly.
    float y[12];
    #pragma unroll
    for (int t = 0; t < 12; ++t) {
        float d = dot4(x[t], w4);
        #pragma unroll
        for (int off = 1; off < 64; off <<= 1) d += __shfl_xor(d, off);
        y[t] = d;
    }

    // Window sums (raw, means applied below).
    const float s2_0 = y[0]+y[1],  s2_1 = y[2]+y[3],  s2_2 = y[4]+y[5];
    const float s2_3 = y[6]+y[7],  s2_4 = y[8]+y[9],  s2_5 = y[10]+y[11];
    const float s3_0 = y[0]+y[1]+y[2],  s3_1 = y[3]+y[4]+y[5];
    const float s3_2 = y[6]+y[7]+y[8],  s3_3 = y[9]+y[10]+y[11];
    const float s4_0 = s2_0+s2_1, s4_1 = s2_2+s2_3, s4_2 = s2_4+s2_5;

    // Each lane l<12 computes its position's coefficients (others harmless).
    const int l = lane;
    const float m1 = sel12(l, y[0],y[1],y[2],y[3],y[4],y[5],
                              y[6],y[7],y[8],y[9],y[10],y[11]);
    const float m2 = 0.5f        * sel6(l >> 1, s2_0,s2_1,s2_2,s2_3,s2_4,s2_5);
    const float m3 = (1.f/3.f)   * sel4(l / 3, s3_0,s3_1,s3_2,s3_3);
    const float m4 = 0.25f       * sel3(l >> 2, s4_0,s4_1,s4_2);

    float sc0 = m1 + bias, sc1 = m2 + bias, sc2 = m3 + bias, sc3 = m4 + bias;
    const float mx = fmaxf(fmaxf(sc0, sc1), fmaxf(sc2, sc3));
    float p0 = expf(sc0 - mx), p1 = expf(sc1 - mx),
          p2 = expf(sc2 - mx), p3 = expf(sc3 - mx);
    const float pinv = 1.f / (p0 + p1 + p2 + p3);
    p0 *= pinv; p1 *= pinv; p2 *= pinv; p3 *= pinv;

    float sn[4];
    #pragma unroll
    for (int i = 0; i < 4; ++i) {
        const float pi = i == 0 ? p0 : i == 1 ? p1 : i == 2 ? p2 : p3;
        const float q0 = pi*p0, q1 = pi*p1, q2 = pi*p2, q3 = pi*p3;
        const float mq = fmaxf(fmaxf(q0, q1), fmaxf(q2, q3));
        const float e0 = expf(q0-mq), e1 = expf(q1-mq),
                    e2 = expf(q2-mq), e3 = expf(q3-mq);
        sn[i] = (e0*p0 + e1*p1 + e2*p2 + e3*p3) / (e0+e1+e2+e3);
    }
    // Fold 1/m of the pool mean into the coefficients.
    const float cc0 = sn[0], cc1 = sn[1]*0.5f, cc2 = sn[2]*(1.f/3.f), cc3 = sn[3]*0.25f;

    // 3- and 4-window x sums (registers, constant-indexed under unroll).
    float4 T[4], F[3];
    T[0] = f4add(f4add(x[0], x[1]), x[2]);
    T[1] = f4add(f4add(x[3], x[4]), x[5]);
    T[2] = f4add(f4add(x[6], x[7]), x[8]);
    T[3] = f4add(f4add(x[9], x[10]), x[11]);
    F[0] = f4add(f4add(x[0], x[1]), f4add(x[2], x[3]));
    F[1] = f4add(f4add(x[4], x[5]), f4add(x[6], x[7]));
    F[2] = f4add(f4add(x[8], x[9]), f4add(x[10], x[11]));

    // Combine + folded k=2 output pool: out[r] = (comb[2r]+comb[2r+1])/2.
    float4* out4 = (float4*)out;
    const long obase = (long)b * OUTL + g * 6;
    #pragma unroll
    for (int r = 0; r < 6; ++r) {
        const int l0 = 2*r, l1 = 2*r + 1;
        const float ca0 = __shfl(cc0, l0), ca1 = __shfl(cc1, l0),
                    ca2 = __shfl(cc2, l0), ca3 = __shfl(cc3, l0);
        const float cb0 = __shfl(cc0, l1), cb1 = __shfl(cc1, l1),
                    cb2 = __shfl(cc2, l1), cb3 = __shfl(cc3, l1);
        float4 acc = make_float4(0.f, 0.f, 0.f, 0.f);
        acc = f4fma(acc, ca0, x[l0]);
        acc = f4fma(acc, cb0, x[l1]);
        acc = f4fma(acc, ca1 + cb1, f4add(x[l0], x[l1]));
        acc = f4fma(acc, ca2, T[l0 / 3]);
        acc = f4fma(acc, cb2, T[l1 / 3]);
        acc = f4fma(acc, ca3 + cb3, F[r >> 1]);
        acc.x *= 0.5f; acc.y *= 0.5f; acc.z *= 0.5f; acc.w *= 0.5f;
        out4[(obase + r) * 64 + lane] = acc;
    }
}

extern "C" void kernel_launch(void* const* d_in, const int* in_sizes, int n_in,
                              void* d_out, int out_size, void* d_ws, size_t ws_size,
                              hipStream_t stream) {
    const int*   ids = (const int*)d_in[0];
    const float* E   = (const float*)d_in[1];
    const float* w   = (const float*)d_in[2];
    const float* bsc = (const float*)d_in[3];
    float*       out = (float*)d_out;

    gbst_kernel<<<NBLK, 256, 0, stream>>>(ids, E, w, bsc, out);
}

// Round 5
// 73.022 us; speedup vs baseline: 1.4464x; 1.0438x over previous
//
#include <hip/hip_runtime.h>
#include <math.h>

// GBST fused single-kernel for MI355X — zero-DS register version.
// B=16, L=3072, H=256, VOCAB=256, MAX_BLOCK=4, DOWNSAMPLE=2.
//
// One 64-lane wave owns one 12-position group (12 = lcm(1..4), 12 | SEQ, so
// every bs-window and the k=2 output pool are group-local). Lane = float4
// h-slice. No LDS, no __syncthreads, and NO DS-pipe ops:
//  - ids: readfirstlane-uniform base -> scalar/uniform loads, no bpermute
//  - y-reduction: DPP row_shr/bcast adds (VALU) + readlane(63) -> SGPR
//  - coeff broadcast: v_readlane -> SGPR scalars into v_fma
//  - PE trig: 2 sinf + 2 cosf + 2 expf + angle-addition recurrence
// R3 lesson: 120 ds-shuffles/wave in dependent chains + 16 libm trig were
// the latency; R2 lesson: no LDS tile / barriers; R1: no precompute dispatch.
// (R4 bench was a GPU-acquisition timeout; this is the same kernel resubmitted.)

#define BATCH 16
#define SEQ   3072
#define EMBED 256
#define OUTL  (SEQ / 2)            // 1536
#define GPB   (SEQ / 12)           // 256 groups per batch
#define WPB   4                    // waves per block
#define NBLK  (BATCH * GPB / WPB)  // 1024

__device__ inline float4 f4add(float4 a, float4 b) {
    return make_float4(a.x + b.x, a.y + b.y, a.z + b.z, a.w + b.w);
}
__device__ inline float4 f4fma(float4 acc, float s, float4 a) {
    acc.x += s * a.x; acc.y += s * a.y; acc.z += s * a.z; acc.w += s * a.w;
    return acc;
}
__device__ inline float dot4(float4 a, float4 b) {
    return a.x * b.x + a.y * b.y + a.z * b.z + a.w * b.w;
}

// DPP-based wave64 sum (VALU only, no DS). Result valid in lane 63.
#define DPP_ADD(x, ctrl, rmask)                                            \
    ((x) + __int_as_float(__builtin_amdgcn_update_dpp(                      \
               0, __float_as_int(x), (ctrl), (rmask), 0xf, true)))
__device__ inline float wave_sum_to63(float x) {
    x = DPP_ADD(x, 0x111, 0xf);   // row_shr:1
    x = DPP_ADD(x, 0x112, 0xf);   // row_shr:2
    x = DPP_ADD(x, 0x114, 0xf);   // row_shr:4
    x = DPP_ADD(x, 0x118, 0xf);   // row_shr:8  -> lane15 of each row = row sum
    x = DPP_ADD(x, 0x142, 0xa);   // row_bcast15 -> rows 1,3
    x = DPP_ADD(x, 0x143, 0xc);   // row_bcast31 -> rows 2,3; lane63 = total
    return x;
}
__device__ inline float bcast_lane(float x, int l) {
    return __int_as_float(__builtin_amdgcn_readlane(__float_as_int(x), l));
}

// Constant-operand select trees (register cndmasks; no local arrays).
__device__ inline float sel12(int i, const float* a) {
    return i == 0 ? a[0] : i == 1 ? a[1] : i == 2 ? a[2] : i == 3 ? a[3] :
           i == 4 ? a[4] : i == 5 ? a[5] : i == 6 ? a[6] : i == 7 ? a[7] :
           i == 8 ? a[8] : i == 9 ? a[9] : i == 10 ? a[10] : a[11];
}
__device__ inline float sel6(int i, float a0, float a1, float a2,
                             float a3, float a4, float a5) {
    return i == 0 ? a0 : i == 1 ? a1 : i == 2 ? a2 :
           i == 3 ? a3 : i == 4 ? a4 : a5;
}
__device__ inline float sel4(int i, float a0, float a1, float a2, float a3) {
    return i == 0 ? a0 : i == 1 ? a1 : i == 2 ? a2 : a3;
}
__device__ inline float sel3(int i, float a0, float a1, float a2) {
    return i == 0 ? a0 : i == 1 ? a1 : a2;
}

__global__ __launch_bounds__(256) void gbst_kernel(
        const int* __restrict__ ids, const float* __restrict__ E,
        const float* __restrict__ w, const float* __restrict__ b_score,
        float* __restrict__ out) {
    const int lane = threadIdx.x & 63;
    // Force the group index uniform so id loads scalarize and gather bases
    // live in SGPRs (no per-lane address chains, no bpermute).
    const int grpu = __builtin_amdgcn_readfirstlane(
        (int)(blockIdx.x * WPB + (threadIdx.x >> 6)));
    const int b    = grpu >> 8;          // GPB = 256
    const int g    = grpu & 255;
    const int pos0 = g * 12;             // divisible by 12 -> by 2,3,4

    // Uniform loads: 12 ids + bias. Issued first; latency hides under trig.
    const int4* idp = (const int4*)(ids + b * SEQ + pos0);
    const int4 ia = idp[0], ib = idp[1], ic = idp[2];
    const float bias = b_score[0];
    const float4 w4 = ((const float4*)w)[lane];

    // Issue all 12 row gathers back-to-back (addresses SGPR + lane offset).
    const float4* E4 = (const float4*)E;
    float4 e0  = E4[ia.x * 64 + lane], e1  = E4[ia.y * 64 + lane];
    float4 e2  = E4[ia.z * 64 + lane], e3  = E4[ia.w * 64 + lane];
    float4 e4  = E4[ib.x * 64 + lane], e5  = E4[ib.y * 64 + lane];
    float4 e6  = E4[ib.z * 64 + lane], e7  = E4[ib.w * 64 + lane];
    float4 e8  = E4[ic.x * 64 + lane], e9  = E4[ic.y * 64 + lane];
    float4 e10 = E4[ic.z * 64 + lane], e11 = E4[ic.w * 64 + lane];

    // PE for this lane's h-slice (h = 4*lane..4*lane+3), q = pos % 4.
    // Base angles once; q=2,3 via angle-addition (saves 16 libm calls).
    const float c1 = -0.035977892080032f;           // -ln(1e4)/256
    const float da = __expf((float)(4 * lane) * c1);
    const float db = __expf((float)(4 * lane + 2) * c1);
    const float sa1 = __sinf(da), ca1 = __cosf(da);
    const float sb1 = __sinf(db), cb1 = __cosf(db);
    const float sa2 = 2.f * sa1 * ca1,  ca2 = 1.f - 2.f * sa1 * sa1;
    const float sb2 = 2.f * sb1 * cb1,  cb2 = 1.f - 2.f * sb1 * sb1;
    const float sa3 = sa2 * ca1 + ca2 * sa1, ca3 = ca2 * ca1 - sa2 * sa1;
    const float sb3 = sb2 * cb1 + cb2 * sb1, cb3 = cb2 * cb1 - sb2 * sb1;
    const float4 pe0 = make_float4(0.f, 1.f, 0.f, 1.f);
    const float4 pe1 = make_float4(sa1, ca1, sb1, cb1);
    const float4 pe2 = make_float4(sa2, ca2, sb2, cb2);
    const float4 pe3 = make_float4(sa3, ca3, sb3, cb3);

    float4 x[12];
    x[0] = f4add(e0, pe0);  x[1] = f4add(e1, pe1);
    x[2] = f4add(e2, pe2);  x[3] = f4add(e3, pe3);
    x[4] = f4add(e4, pe0);  x[5] = f4add(e5, pe1);
    x[6] = f4add(e6, pe2);  x[7] = f4add(e7, pe3);
    x[8] = f4add(e8, pe0);  x[9] = f4add(e9, pe1);
    x[10] = f4add(e10, pe2); x[11] = f4add(e11, pe3);

    // y[t] = dot(x[t], w) reduced across the wave via DPP; uniform via
    // readlane(63). 12 independent trees pipeline on the VALU.
    float y[12];
    #pragma unroll
    for (int t = 0; t < 12; ++t)
        y[t] = bcast_lane(wave_sum_to63(dot4(x[t], w4)), 63);

    // Window sums (uniform scalars).
    const float s2_0 = y[0]+y[1],  s2_1 = y[2]+y[3],  s2_2 = y[4]+y[5];
    const float s2_3 = y[6]+y[7],  s2_4 = y[8]+y[9],  s2_5 = y[10]+y[11];
    const float s3_0 = y[0]+y[1]+y[2],  s3_1 = y[3]+y[4]+y[5];
    const float s3_2 = y[6]+y[7]+y[8],  s3_3 = y[9]+y[10]+y[11];
    const float s4_0 = s2_0+s2_1, s4_1 = s2_2+s2_3, s4_2 = s2_4+s2_5;

    // Lane l<12 computes position l's softmax + 4x4 calibration.
    const int l = lane;
    const float m1 = sel12(l, y);
    const float m2 = 0.5f      * sel6(l >> 1, s2_0,s2_1,s2_2,s2_3,s2_4,s2_5);
    const float m3 = (1.f/3.f) * sel4(l / 3, s3_0,s3_1,s3_2,s3_3);
    const float m4 = 0.25f     * sel3(l >> 2, s4_0,s4_1,s4_2);

    const float sc0 = m1 + bias, sc1 = m2 + bias, sc2 = m3 + bias, sc3 = m4 + bias;
    const float mx = fmaxf(fmaxf(sc0, sc1), fmaxf(sc2, sc3));
    float p0 = expf(sc0 - mx), p1 = expf(sc1 - mx),
          p2 = expf(sc2 - mx), p3 = expf(sc3 - mx);
    const float pinv = 1.f / (p0 + p1 + p2 + p3);
    p0 *= pinv; p1 *= pinv; p2 *= pinv; p3 *= pinv;

    float sn[4];
    #pragma unroll
    for (int i = 0; i < 4; ++i) {
        const float pi = i == 0 ? p0 : i == 1 ? p1 : i == 2 ? p2 : p3;
        const float q0 = pi*p0, q1 = pi*p1, q2 = pi*p2, q3 = pi*p3;
        const float mq = fmaxf(fmaxf(q0, q1), fmaxf(q2, q3));
        const float f0 = expf(q0-mq), f1 = expf(q1-mq),
                    f2 = expf(q2-mq), f3 = expf(q3-mq);
        sn[i] = (f0*p0 + f1*p1 + f2*p2 + f3*p3) / (f0+f1+f2+f3);
    }
    const float cc0 = sn[0], cc1 = sn[1]*0.5f,
                cc2 = sn[2]*(1.f/3.f), cc3 = sn[3]*0.25f;

    // Broadcast the 12x4 coefficients to SGPRs via readlane (VALU, no DS).
    float C0[12], C1[12], C2[12], C3[12];
    #pragma unroll
    for (int t = 0; t < 12; ++t) {
        C0[t] = bcast_lane(cc0, t);
        C1[t] = bcast_lane(cc1, t);
        C2[t] = bcast_lane(cc2, t);
        C3[t] = bcast_lane(cc3, t);
    }

    // 3- and 4-window x sums.
    float4 T[4], F[3];
    T[0] = f4add(f4add(x[0], x[1]), x[2]);
    T[1] = f4add(f4add(x[3], x[4]), x[5]);
    T[2] = f4add(f4add(x[6], x[7]), x[8]);
    T[3] = f4add(f4add(x[9], x[10]), x[11]);
    F[0] = f4add(f4add(x[0], x[1]), f4add(x[2], x[3]));
    F[1] = f4add(f4add(x[4], x[5]), f4add(x[6], x[7]));
    F[2] = f4add(f4add(x[8], x[9]), f4add(x[10], x[11]));

    // Combine + folded k=2 output pool: out[r] = (comb[2r]+comb[2r+1])/2.
    float4* out4 = (float4*)out;
    const long obase = (long)b * OUTL + g * 6;
    #pragma unroll
    for (int r = 0; r < 6; ++r) {
        const int l0 = 2*r, l1 = 2*r + 1;
        float4 acc = make_float4(0.f, 0.f, 0.f, 0.f);
        acc = f4fma(acc, C0[l0], x[l0]);
        acc = f4fma(acc, C0[l1], x[l1]);
        acc = f4fma(acc, C1[l0] + C1[l1], f4add(x[l0], x[l1]));
        acc = f4fma(acc, C2[l0], T[l0 / 3]);
        acc = f4fma(acc, C2[l1], T[l1 / 3]);
        acc = f4fma(acc, C3[l0] + C3[l1], F[r >> 1]);
        acc.x *= 0.5f; acc.y *= 0.5f; acc.z *= 0.5f; acc.w *= 0.5f;
        out4[(obase + r) * 64 + lane] = acc;
    }
}

extern "C" void kernel_launch(void* const* d_in, const int* in_sizes, int n_in,
                              void* d_out, int out_size, void* d_ws, size_t ws_size,
                              hipStream_t stream) {
    const int*   ids = (const int*)d_in[0];
    const float* E   = (const float*)d_in[1];
    const float* w   = (const float*)d_in[2];
    const float* bsc = (const float*)d_in[3];
    float*       out = (float*)d_out;

    gbst_kernel<<<NBLK, 256, 0, stream>>>(ids, E, w, bsc, out);
}